// Round 1
// baseline (180.254 us; speedup 1.0000x reference)
//
#include <hip/hip_runtime.h>
#include <math.h>

#define T_   100
#define D_   50
#define BS_  2
#define CH_  100
#define RI_  12
#define RC_  16
#define KNN_ 3
#define QD_  (CH_ * (RI_ + RC_))   // 2800
#define TOTAL_ (BS_ * QD_ * D_ * T_)  // 28,000,000

// Kernel 1: one block per (b, t).
// Computes pd[t, s] = 2*dot(x[b,:,t], x[b,:,s]) - sum_c x[b,c,t]^3 - sum_c x[b,c,s]^3,
// takes top-3 s (ties -> lowest index, matching lax.top_k), and stores
// ctx[b, t, k] = mean_c x[b, c, idx_k].
__global__ __launch_bounds__(128) void ctx_kernel(const float* __restrict__ x,
                                                  float* __restrict__ ctx) {
    __shared__ float xs[CH_ * T_];   // x[b] staged, layout [c][s]
    __shared__ float key[T_];        // 2*dot(t, s)
    __shared__ float css[T_];        // sum_c x[c,s]^3
    __shared__ float cm[T_];         // mean_c x[c,s]

    const int blk = blockIdx.x;
    const int b = blk / T_;
    const int t = blk - b * T_;
    const float* xb = x + b * CH_ * T_;

    // Stage x[b] (40 KB) into LDS with float4 loads (10000 % 4 == 0).
    const float4* xb4 = (const float4*)xb;
    float4* xs4 = (float4*)xs;
    for (int i = threadIdx.x; i < (CH_ * T_) / 4; i += blockDim.x)
        xs4[i] = xb4[i];
    __syncthreads();

    const int s = threadIdx.x;
    if (s < T_) {
        float dot = 0.f, cube = 0.f, colsum = 0.f;
        #pragma unroll 4
        for (int c = 0; c < CH_; ++c) {
            float v  = xs[c * T_ + s];   // stride-1 across lanes: conflict-free
            float vt = xs[c * T_ + t];   // uniform: broadcast
            dot    += v * vt;
            cube   += v * v * v;
            colsum += v;
        }
        key[s] = 2.f * dot;
        css[s] = cube;
        cm[s]  = colsum * (1.0f / (float)CH_);
    }
    __syncthreads();

    if (threadIdx.x == 0) {
        // top-3 scan; - css[t] is a uniform shift, irrelevant to ordering.
        int chosen0 = -1, chosen1 = -1;
        for (int k = 0; k < KNN_; ++k) {
            float best = -INFINITY;
            int bi = 0;
            for (int ss = 0; ss < T_; ++ss) {
                if (ss == chosen0 || ss == chosen1) continue;
                float v = key[ss] - css[ss];
                if (v > best) { best = v; bi = ss; }  // strict >: ties keep lowest index
            }
            ctx[(b * T_ + t) * KNN_ + k] = cm[bi];
            if (k == 0) chosen0 = bi; else chosen1 = bi;
        }
    }
}

// Kernel 2: one thread per 4 consecutive output elements (same (b, c, j, du),
// s = s0..s0+3, since 100 % 4 == 0). float4 coalesced store.
// out[((b*2800 + c*28 + j)*50 + du)*100 + s]
__global__ __launch_bounds__(256) void out_kernel(const float* __restrict__ x,
                                                  const float* __restrict__ anchors,
                                                  const float* __restrict__ ctx,
                                                  float* __restrict__ out) {
    int o4 = blockIdx.x * blockDim.x + threadIdx.x;
    if (o4 >= TOTAL_ / 4) return;
    int o = o4 * 4;

    int s0  = o % T_;
    int rem = o / T_;           // (b*2800 + q)*50 + du
    int du  = rem % D_;
    int bq  = rem / D_;         // b*2800 + q
    int q   = bq % QD_;
    int b   = bq / QD_;
    int c   = q / (RI_ + RC_);
    int j   = q - c * (RI_ + RC_);

    const bool inner = (j < RI_);
    // jsc = (j + 0.5) / res  (inexact 1/res is safe: coords can never hit an
    // integer or the validity boundary exactly — odd/24 rationals).
    const float jsc = inner ? ((float)j + 0.5f) * (1.0f / (float)RI_)
                            : ((float)(j - RI_) + 0.5f) * (1.0f / (float)RC_);
    const float Lf  = inner ? (float)T_ : (float)KNN_;
    const int   Lm1 = inner ? (T_ - 1) : (KNN_ - 1);
    const float* fr = inner ? (x + (b * CH_ + c) * T_)
                            : (ctx + (b * T_ + c) * KNN_);

    float res[4];
    #pragma unroll
    for (int i = 0; i < 4; ++i) {
        int sidx = s0 + i;
        int r = (b * T_ + sidx) * D_ + du;       // anchor row
        float start = anchors[3 * r + 1];
        float end   = anchors[3 * r + 2];
        float coord = start + jsc * (end - start);
        bool valid = (coord >= -1.0f) && (coord <= Lf);
        float lo = floorf(coord);
        float frac = coord - lo;
        int loi = (int)lo;
        loi = loi < 0 ? 0 : (loi > Lm1 ? Lm1 : loi);
        int hii = loi + 1 > Lm1 ? Lm1 : loi + 1;
        float v = fr[loi] * (1.0f - frac) + fr[hii] * frac;
        res[i] = valid ? v : 0.0f;
    }
    *(float4*)(out + o) = *(float4*)res;
}

extern "C" void kernel_launch(void* const* d_in, const int* in_sizes, int n_in,
                              void* d_out, int out_size, void* d_ws, size_t ws_size,
                              hipStream_t stream) {
    const float* x       = (const float*)d_in[0];
    const float* anchors = (const float*)d_in[1];
    // d_in[2] (index) is unused by the reference.
    float* ctx = (float*)d_ws;          // 2*100*3 = 600 floats
    float* out = (float*)d_out;

    ctx_kernel<<<BS_ * T_, 128, 0, stream>>>(x, ctx);

    const int n4 = TOTAL_ / 4;          // 7,000,000
    const int blocks = (n4 + 255) / 256;
    out_kernel<<<blocks, 256, 0, stream>>>(x, anchors, ctx, out);
}

// Round 2
// 149.273 us; speedup vs baseline: 1.2075x; 1.2075x over previous
//
#include <hip/hip_runtime.h>
#include <math.h>

#define T_   100
#define D_   50
#define BS_  2
#define CH_  100
#define RI_  12
#define RC_  16
#define KNN_ 3
#define NJ_  (RI_ + RC_)              // 28
#define QD_  (CH_ * NJ_)              // 2800
#define TOTAL_ (BS_ * QD_ * D_ * T_)  // 28,000,000

#define CT_  10    // channels per block tile
#define XP_  104   // padded x-row stride in LDS (100 data + 1 dup)

// ---------------------------------------------------------------------------
// Kernel 1: one block per (b, t). pd[t,s] = 2*dot(x[:,t],x[:,s]) - cube[s]
// (- cube[t] is a uniform shift). Top-3 via wave-0 butterfly argmax
// (tie -> lowest index, matching lax.top_k). ctx[b,t,k] = mean_c x[b,c,idx_k].
// ---------------------------------------------------------------------------
__global__ __launch_bounds__(128) void ctx_kernel(const float* __restrict__ x,
                                                  float* __restrict__ ctx) {
    __shared__ float xs[CH_ * T_];   // x[b], layout [c][s]
    __shared__ float cm[T_];         // column means
    __shared__ float va[128];        // argmax keys

    const int b = blockIdx.x / T_;
    const int t = blockIdx.x - b * T_;
    const float* xb = x + b * CH_ * T_;

    const float4* xb4 = (const float4*)xb;
    float4* xs4 = (float4*)xs;
    for (int i = threadIdx.x; i < (CH_ * T_) / 4; i += 128) xs4[i] = xb4[i];
    __syncthreads();

    const int s = threadIdx.x;
    float v = -INFINITY;
    if (s < T_) {
        float dot = 0.f, cube = 0.f, colsum = 0.f;
        #pragma unroll 4
        for (int c = 0; c < CH_; ++c) {
            float vv = xs[c * T_ + s];   // stride-1 across lanes
            float vt = xs[c * T_ + t];   // uniform: broadcast
            dot    += vv * vt;
            cube   += vv * vv * vv;
            colsum += vv;
        }
        v = 2.f * dot - cube;            // same value/order as serial version
        cm[s] = colsum * (1.0f / (float)CH_);
    }
    va[threadIdx.x] = v;
    __syncthreads();

    if (threadIdx.x < 64) {              // wave 0 only
        const int l = threadIdx.x;
        const float c0v = va[l];
        const float c1v = va[l + 64];    // -inf for s >= 100
        int sel0 = -100, sel1 = -100;
        for (int k = 0; k < KNN_; ++k) {
            float v0 = (l == sel0 || l == sel1) ? -INFINITY : c0v;
            float v1 = (l + 64 == sel0 || l + 64 == sel1) ? -INFINITY : c1v;
            float bv; int bi;
            if (v1 > v0) { bv = v1; bi = l + 64; } else { bv = v0; bi = l; }
            #pragma unroll
            for (int off = 32; off > 0; off >>= 1) {
                float ov = __shfl_xor(bv, off);
                int   oi = __shfl_xor(bi, off);
                if (ov > bv || (ov == bv && oi < bi)) { bv = ov; bi = oi; }
            }
            if (l == 0) ctx[(b * T_ + t) * KNN_ + k] = cm[bi];
            if (k == 0) sel0 = bi; else sel1 = bi;
        }
    }
}

// ---------------------------------------------------------------------------
// Kernel 2: one block per (b, du, c-tile). Params (coord/lo/frac/valid) depend
// only on (s, j) for fixed (b, du): computed ONCE into LDS, reused by all
// CT_ channels. Value reads come from LDS-staged x/ctx rows padded with a
// duplicated last element so hi = lo+1 unconditionally. Stores: float4,
// coalesced in s.  out[((b*2800 + c*28 + j)*50 + du)*100 + s]
// ---------------------------------------------------------------------------
__global__ __launch_bounds__(256) void out_kernel(const float* __restrict__ x,
                                                  const float* __restrict__ anchors,
                                                  const float* __restrict__ ctx,
                                                  float* __restrict__ out) {
    __shared__ float an_s[T_], an_e[T_];
    __shared__ alignas(16) float frac_a[NJ_ * T_];  // [j][s]
    __shared__ alignas(16) int   lo_a[NJ_ * T_];    // -1 = invalid
    __shared__ float xs[CT_ * XP_];                 // padded x rows
    __shared__ float cs[CT_ * 4];                   // padded ctx rows

    const int nct = CH_ / CT_;
    const int ct  = blockIdx.x % nct;
    const int du  = (blockIdx.x / nct) % D_;
    const int b   = blockIdx.x / (nct * D_);
    const int c0  = ct * CT_;
    const int tid = threadIdx.x;

    // --- stage anchors for (b, :, du) ---
    if (tid < T_) {
        int r = (b * T_ + tid) * D_ + du;
        an_s[tid] = anchors[3 * r + 1];
        an_e[tid] = anchors[3 * r + 2];
    }
    // --- stage x tile (rows c0..c0+CT_-1), padded ---
    const float* xg = x + (b * CH_ + c0) * T_;
    for (int i = tid; i < CT_ * T_; i += 256) {
        int cl = i / T_, ss = i - cl * T_;
        xs[cl * XP_ + ss] = xg[i];
    }
    if (tid < CT_) xs[tid * XP_ + T_] = xg[tid * T_ + (T_ - 1)];
    // --- stage ctx tile, padded ---
    if (tid < CT_) {
        const float* cg = ctx + (b * T_ + c0 + tid) * KNN_;
        cs[tid * 4 + 0] = cg[0];
        cs[tid * 4 + 1] = cg[1];
        cs[tid * 4 + 2] = cg[2];
        cs[tid * 4 + 3] = cg[2];
    }
    __syncthreads();

    // --- interpolation params, once per (j, s) ---
    for (int p = tid; p < NJ_ * T_; p += 256) {
        int j = p / T_;
        int s = p - j * T_;
        bool inner = j < RI_;
        float jsc = inner ? ((float)j + 0.5f) * (1.0f / (float)RI_)
                          : ((float)(j - RI_) + 0.5f) * (1.0f / (float)RC_);
        float st = an_s[s], en = an_e[s];
        float coord = st + jsc * (en - st);
        float Lf  = inner ? (float)T_ : (float)KNN_;
        int   Lm1 = inner ? (T_ - 1) : (KNN_ - 1);
        bool valid = (coord >= -1.0f) && (coord <= Lf);
        float lof = floorf(coord);
        int lo = (int)lof;
        lo = lo < 0 ? 0 : (lo > Lm1 ? Lm1 : lo);
        frac_a[p] = coord - lof;
        lo_a[p]   = valid ? lo : -1;
    }
    __syncthreads();

    // --- emit: CT_*28*25 float4 per block ---
    for (int e4 = tid; e4 < CT_ * NJ_ * (T_ / 4); e4 += 256) {
        int cl  = e4 / (NJ_ * (T_ / 4));
        int rem = e4 - cl * (NJ_ * (T_ / 4));
        int j   = rem / (T_ / 4);
        int s4  = rem - j * (T_ / 4);
        const float* fr = (j < RI_) ? &xs[cl * XP_] : &cs[cl * 4];
        int p = j * T_ + s4 * 4;
        float4 f4 = *(const float4*)&frac_a[p];
        int4   l4 = *(const int4*)&lo_a[p];
        int   lv[4] = {l4.x, l4.y, l4.z, l4.w};
        float fv[4] = {f4.x, f4.y, f4.z, f4.w};
        float res[4];
        #pragma unroll
        for (int i = 0; i < 4; ++i) {
            int le = lv[i];
            int lu = le < 0 ? 0 : le;
            float f = fv[i];
            float vv = fr[lu] * (1.0f - f) + fr[lu + 1] * f;
            res[i] = le < 0 ? 0.0f : vv;
        }
        float4 ov = make_float4(res[0], res[1], res[2], res[3]);
        *(float4*)(out + ((((b * QD_ + (c0 + cl) * NJ_ + j) * D_) + du) * T_ + s4 * 4)) = ov;
    }
}

extern "C" void kernel_launch(void* const* d_in, const int* in_sizes, int n_in,
                              void* d_out, int out_size, void* d_ws, size_t ws_size,
                              hipStream_t stream) {
    const float* x       = (const float*)d_in[0];
    const float* anchors = (const float*)d_in[1];
    float* ctx = (float*)d_ws;     // 2*100*3 = 600 floats
    float* out = (float*)d_out;

    ctx_kernel<<<BS_ * T_, 128, 0, stream>>>(x, ctx);

    const int blocks = BS_ * D_ * (CH_ / CT_);   // 1000
    out_kernel<<<blocks, 256, 0, stream>>>(x, anchors, ctx, out);
}

// Round 3
// 140.343 us; speedup vs baseline: 1.2844x; 1.0636x over previous
//
#include <hip/hip_runtime.h>
#include <math.h>

#define T_   100
#define D_   50
#define BS_  2
#define CH_  100
#define RI_  12
#define RC_  16
#define KNN_ 3
#define NJ_  (RI_ + RC_)              // 28
#define QD_  (CH_ * NJ_)              // 2800
#define CT_  5                        // channels per block
#define XPS_ 104                      // skewed row stride: skew(100)=103 max

// ---------------------------------------------------------------------------
// Kernel 1: one block per (b, t). key[s] = 2*dot(x[:,t],x[:,s]) - cube[s]
// (-cube[t] is a uniform shift). x read DIRECTLY from global (80 KB total,
// L1/L2-resident): x[c,s] coalesced across lanes, x[c,t] uniform (scalar).
// Top-3 via wave-0 butterfly argmax (tie -> lowest index = lax.top_k).
// ctx[b,t,k] = mean_c x[b,c,idx_k].
// ---------------------------------------------------------------------------
__global__ __launch_bounds__(128) void ctx_kernel(const float* __restrict__ x,
                                                  float* __restrict__ ctx) {
    __shared__ float cm[T_];
    __shared__ float va[128];

    const int b = blockIdx.x / T_;
    const int t = blockIdx.x - b * T_;
    const float* xb = x + b * CH_ * T_;
    const int s = threadIdx.x;

    float key = -INFINITY;
    if (s < T_) {
        float dot = 0.f, cube = 0.f, colsum = 0.f;
        #pragma unroll 10
        for (int c = 0; c < CH_; ++c) {
            float vv = xb[c * T_ + s];   // coalesced across lanes
            float vt = xb[c * T_ + t];   // uniform -> scalar load
            dot    += vv * vt;
            cube   += vv * vv * vv;
            colsum += vv;
        }
        key = 2.f * dot - cube;
        cm[s] = colsum * (1.0f / (float)CH_);
    }
    va[threadIdx.x] = key;
    __syncthreads();

    if (threadIdx.x < 64) {              // wave 0 only
        const int l = threadIdx.x;
        const float c0v = va[l];
        const float c1v = va[l + 64];    // -inf for s >= 100
        int sel0 = -100, sel1 = -100;
        for (int k = 0; k < KNN_; ++k) {
            float v0 = (l == sel0 || l == sel1) ? -INFINITY : c0v;
            float v1 = (l + 64 == sel0 || l + 64 == sel1) ? -INFINITY : c1v;
            float bv; int bi;
            if (v1 > v0) { bv = v1; bi = l + 64; } else { bv = v0; bi = l; }
            #pragma unroll
            for (int off = 32; off > 0; off >>= 1) {
                float ov = __shfl_xor(bv, off);
                int   oi = __shfl_xor(bi, off);
                if (ov > bv || (ov == bv && oi < bi)) { bv = ov; bi = oi; }
            }
            if (l == 0) ctx[(b * T_ + t) * KNN_ + k] = cm[bi];
            if (k == 0) sel0 = bi; else sel1 = bi;
        }
    }
}

// ---------------------------------------------------------------------------
// Kernel 2: one block per (b, du, 5-channel tile); 704 threads, one thread
// per (j, s4) work item (700 active). Interp params live in REGISTERS
// (computed once), channel loop inside. x rows staged in LDS with a
// skew (p = i + i/32) so the natural lane-stride-4 gather is 2-way (free)
// instead of 8-way conflicted. hi = lo+1 via duplicated top element.
// out[((b*2800 + c*28 + j)*50 + du)*100 + s], float4 stores.
// ---------------------------------------------------------------------------
__global__ __launch_bounds__(704) void out_kernel(const float* __restrict__ x,
                                                  const float* __restrict__ anchors,
                                                  const float* __restrict__ ctx,
                                                  float* __restrict__ out) {
    __shared__ float an_s[T_], an_e[T_];
    __shared__ float xs[CT_ * XPS_];
    __shared__ float cs[CT_ * 4];

    const int nct = CH_ / CT_;            // 20
    const int ct  = blockIdx.x % nct;
    const int du  = (blockIdx.x / nct) % D_;
    const int b   = blockIdx.x / (nct * D_);
    const int c0  = ct * CT_;
    const int tid = threadIdx.x;

    // anchors (b, :, du): 200 lanes, one float each
    if (tid < 2 * T_) {
        int ss = tid >> 1, comp = tid & 1;
        int r = (b * T_ + ss) * D_ + du;
        float v = anchors[3 * r + 1 + comp];
        if (comp) an_e[ss] = v; else an_s[ss] = v;
    }
    // x rows (skewed) + ctx rows (+ dup top elements)
    if (tid < CT_ * T_) {                 // 500
        int cl = tid / T_, ss = tid - cl * T_;
        xs[cl * XPS_ + ss + (ss >> 5)] = x[(b * CH_ + c0 + cl) * T_ + ss];
    }
    if (tid >= 512 && tid < 512 + CT_) {
        int cl = tid - 512;
        xs[cl * XPS_ + 103] = x[(b * CH_ + c0 + cl) * T_ + (T_ - 1)];  // skew(100)=103
    }
    if (tid >= 520 && tid < 520 + CT_) {
        int cl = tid - 520;
        const float* cg = ctx + (b * T_ + c0 + cl) * KNN_;
        cs[cl * 4 + 0] = cg[0];
        cs[cl * 4 + 1] = cg[1];
        cs[cl * 4 + 2] = cg[2];
        cs[cl * 4 + 3] = cg[2];           // dup: hi clamp
    }
    __syncthreads();

    if (tid >= NJ_ * (T_ / 4)) return;    // 700 active
    const int j  = tid / (T_ / 4);
    const int s4 = tid - j * (T_ / 4);
    const int s0 = s4 * 4;
    const bool inner = (j < RI_);
    const float jsc = inner ? ((float)j + 0.5f) * (1.0f / (float)RI_)
                            : ((float)(j - RI_) + 0.5f) * (1.0f / (float)RC_);
    const float Lf  = inner ? (float)T_ : (float)KNN_;
    const int   Lm1 = inner ? (T_ - 1) : (KNN_ - 1);
    const float* fb   = inner ? xs : cs;
    const int rstride = inner ? XPS_ : 4;

    // params in registers, once
    int pl_[4], ph_[4];
    float f_[4], msk[4];
    #pragma unroll
    for (int i = 0; i < 4; ++i) {
        float st = an_s[s0 + i], en = an_e[s0 + i];
        float coord = st + jsc * (en - st);
        msk[i] = ((coord >= -1.0f) && (coord <= Lf)) ? 1.0f : 0.0f;
        float lof = floorf(coord);
        f_[i] = coord - lof;
        int lo = (int)lof;
        lo = lo < 0 ? 0 : (lo > Lm1 ? Lm1 : lo);   // med3
        int hi = lo + 1;                            // dup element covers top
        pl_[i] = inner ? lo + (lo >> 5) : lo;       // skew only for x rows
        ph_[i] = inner ? hi + (hi >> 5) : hi;
    }

    int obase = (((b * QD_ + c0 * NJ_ + j) * D_) + du) * T_ + s0;
    const int ostride = NJ_ * D_ * T_;              // 140000
    #pragma unroll
    for (int cl = 0; cl < CT_; ++cl) {
        const float* fr = fb + cl * rstride;
        float res[4];
        #pragma unroll
        for (int i = 0; i < 4; ++i) {
            float f = f_[i];
            res[i] = (fr[pl_[i]] * (1.0f - f) + fr[ph_[i]] * f) * msk[i];
        }
        *(float4*)(out + obase) = make_float4(res[0], res[1], res[2], res[3]);
        obase += ostride;
    }
}

extern "C" void kernel_launch(void* const* d_in, const int* in_sizes, int n_in,
                              void* d_out, int out_size, void* d_ws, size_t ws_size,
                              hipStream_t stream) {
    const float* x       = (const float*)d_in[0];
    const float* anchors = (const float*)d_in[1];
    float* ctx = (float*)d_ws;     // 2*100*3 = 600 floats
    float* out = (float*)d_out;

    ctx_kernel<<<BS_ * T_, 128, 0, stream>>>(x, ctx);

    const int blocks = BS_ * D_ * (CH_ / CT_);   // 2000
    out_kernel<<<blocks, 704, 0, stream>>>(x, anchors, ctx, out);
}